// Round 8
// baseline (23.670 us; speedup 1.0000x reference)
//
#include <hip/hip_runtime.h>

#define NPROTO 20
#define SEQ_LEN 512
#define ROWS_PER_BLOCK 8
#define TPB (ROWS_PER_BLOCK * 64)   // 512 threads = 8 independent waves, no barriers

// Correctly-rounded a/d via Markstein refinement, given rc = RN(1/d), nd = -d:
// q0 = RN(a*rc); r = fma(nd,q0,a) (exact); q1 = RN(q0 + r*rc) == RN(a/d).
// Bit-exact vs IEEE divide for this kernel's operand families (verified
// absmax=0 in R3/R4/R6/R7 over the full input set):
//  - d = 3.0f constant
//  - d = integer in [1,510], a = exact integer product < 2^18
__device__ __forceinline__ float div_exact(float a, float nd, float rc)
{
    const float q0 = a * rc;
    const float r  = fmaf(nd, q0, a);
    return fmaf(r, rc, q0);
}

// One WAVE per batch row; 8 rows per block -> 1024 workgroups (vs 8192),
// attacking the measured ~370 WG/us dispatch floor. No LDS, no barriers.
//  - row is readfirstlane-scalarized; all row inputs are loaded at
//    wave-uniform addresses (SMEM candidates).
//  - the sequential mean (XLA order) is computed redundantly per-lane from
//    register copies: no cross-lane communication at all (R7-proven pattern;
//    avoids R5's failed lane0->LDS broadcast).
//  - per-prototype keep branch is an exec-mask skip over a large body ->
//    non-kept prototypes are dynamically skipped; kept ones accumulate in
//    ascending p, so the rounding sequence equals the reference.
//  - lane owns l = lane*8 .. lane*8+7 (two float4 stores).
__global__ __launch_bounds__(TPB)
void adaptive_mask_kernel(const float* __restrict__ tok,
                          const float* __restrict__ sigma,
                          const float* __restrict__ pi,
                          float* __restrict__ out)
{
    const int lane = threadIdx.x & 63;
    const int wid  = __builtin_amdgcn_readfirstlane((int)(threadIdx.x >> 6));
    const int row  = blockIdx.x * ROWS_PER_BLOCK + wid;

    const float* __restrict__ trow = tok   + row * NPROTO;
    const float* __restrict__ srow = sigma + row * NPROTO;
    const float* __restrict__ prow = pi    + row * NPROTO;

    // wave-uniform preloads (compile-time indices -> registers, no scratch)
    float tk[NPROTO], sg[NPROTO], pv[NPROTO];
    #pragma unroll
    for (int p = 0; p < NPROTO; ++p) {
        tk[p] = trow[p];
        sg[p] = srow[p];
        pv[p] = prow[p];
    }

    // sequential-order mean (bit-exact XLA order), identical in every lane
    float s = 0.0f;
    #pragma unroll
    for (int p = 0; p < NPROTO; ++p) s += pv[p];
    const float mean = s / 20.0f;               // IEEE divide

    const float C3 = 1.0f / 3.0f;               // RN(1/3)
    const float lb = (float)(lane * 8);         // exact
    float acc0 = 0.f, acc1 = 0.f, acc2 = 0.f, acc3 = 0.f;
    float acc4 = 0.f, acc5 = 0.f, acc6 = 0.f, acc7 = 0.f;

    #pragma unroll
    for (int p = 0; p < NPROTO; ++p) {
        if (pv[p] >= mean) {    // same keep rule as ref; all lanes agree ->
                                // exec-mask branch dynamically skips body
            const float m    = rintf(fminf(fmaxf(tk[p], 1.0f), 511.0f));
            const float aL   = (0.001f * sg[p]) * m;             // CVL*sigma*m
            const float aR   = (0.001f * sg[p]) * (512.0f - m);  // CVR*sigma*(512-m)
            const float den  = (m == 511.0f) ? 1.0f : (511.0f - m);
            const float rc   = 1.0f / den;                       // IEEE RN(1/den)
            const float msub = m - 512.0f;                       // exact
            const float nden = -den;                             // exact

#define EVAL(J, ACC)                                                        \
            {                                                               \
                const float lf   = lb + (float)(J);     /* exact int */     \
                const float q    = lf - m;                                  \
                const float num  = q * msub;        /* exact int product */ \
                const float rq   = div_exact(num, nden, rc);                \
                const float left = (q + 1.0f) + aL;                         \
                const float rt   = (-1.0f + rq) + aR;                       \
                const float base = (lf < m) ? left : rt;                    \
                (ACC) += div_exact(base, -3.0f, C3) + 1.0f;                 \
            }

            EVAL(0, acc0) EVAL(1, acc1) EVAL(2, acc2) EVAL(3, acc3)
            EVAL(4, acc4) EVAL(5, acc5) EVAL(6, acc6) EVAL(7, acc7)
#undef EVAL
        }
    }

    float4 r0, r1;
    r0.x = (acc0 > 0.0f) ? 1.0f : 0.0f;
    r0.y = (acc1 > 0.0f) ? 1.0f : 0.0f;
    r0.z = (acc2 > 0.0f) ? 1.0f : 0.0f;
    r0.w = (acc3 > 0.0f) ? 1.0f : 0.0f;
    r1.x = (acc4 > 0.0f) ? 1.0f : 0.0f;
    r1.y = (acc5 > 0.0f) ? 1.0f : 0.0f;
    r1.z = (acc6 > 0.0f) ? 1.0f : 0.0f;
    r1.w = (acc7 > 0.0f) ? 1.0f : 0.0f;

    float4* o = reinterpret_cast<float4*>(out + (size_t)row * SEQ_LEN + lane * 8);
    o[0] = r0;
    o[1] = r1;
}

extern "C" void kernel_launch(void* const* d_in, const int* in_sizes, int n_in,
                              void* d_out, int out_size, void* d_ws, size_t ws_size,
                              hipStream_t stream)
{
    const float* tok   = (const float*)d_in[0];
    const float* sigma = (const float*)d_in[1];
    const float* pi    = (const float*)d_in[2];
    float* out = (float*)d_out;

    const int B = in_sizes[0] / NPROTO;     // 8192
    adaptive_mask_kernel<<<B / ROWS_PER_BLOCK, TPB, 0, stream>>>(tok, sigma, pi, out);
}